// Round 15
// baseline (299.978 us; speedup 1.0000x reference)
//
#include <hip/hip_runtime.h>

#define CC 256
#define NN 4096
#define NB 8
#define NM ((size_t)CC * NN)   // 1M f16 elems per plane

// per-slot plane-0 tail layout (f16-unit offsets within the slot's plane 0).
#define OFF_OVF   589824   // partial rows 2048..2303:  + z*65536 + (row-2048)*256
#define OFF_LM    720896   // float[(z*2304 + row)*2] = {L, M}
#define OFF_POSM  739328   // int[4096] bg compact index or -1
#define OFF_POSF  747520   // int[4096] fg compact index or -1
#define OFF_CNT   755712   // int[2] = {F_b, F_f}
#define OFF_W16   755776   // slot 0 only: f16[4*65536] = Wq,Wk,Wv,Wo
#define PMAIN     524288   // plane 3: + z*PMAIN + row*256, rows 0..2047
#define QCAP      2304     // max compacted q rows (F_f+1; 8 sigma bound)

typedef _Float16 f16;
typedef f16 f16x4 __attribute__((ext_vector_type(4)));
typedef f16 f16x8 __attribute__((ext_vector_type(8)));
typedef float f32x4 __attribute__((ext_vector_type(4)));
typedef unsigned int u32;

// async global->LDS, 16 B per lane; LDS dest = wave-uniform base + lane*16
#define GLD16(gp, lp) __builtin_amdgcn_global_load_lds( \
    (const __attribute__((address_space(1))) u32*)(const void*)(gp), \
    (__attribute__((address_space(3))) u32*)(void*)(lp), 16, 0, 0)

// ---------------------------------------------------------------------------
// wprep: one-time f32->f16 conversion of Wq/Wk/Wv/Wo into slot-0 plane-0 tail.
// ---------------------------------------------------------------------------
__global__ __launch_bounds__(256) void wprep_kernel(
    const float* __restrict__ Wq, const float* __restrict__ Wk,
    const float* __restrict__ Wv, const float* __restrict__ Wo,
    f16* __restrict__ w16)
{
    int i = (blockIdx.x * 256 + threadIdx.x) * 4;   // grid 64 -> covers 65536
    float4 a = *(const float4*)(Wq + i);
    float4 b = *(const float4*)(Wk + i);
    float4 c = *(const float4*)(Wv + i);
    float4 d = *(const float4*)(Wo + i);
    f16x4 ha, hb, hc, hd;
    ha[0]=(f16)a.x; ha[1]=(f16)a.y; ha[2]=(f16)a.z; ha[3]=(f16)a.w;
    hb[0]=(f16)b.x; hb[1]=(f16)b.y; hb[2]=(f16)b.z; hb[3]=(f16)b.w;
    hc[0]=(f16)c.x; hc[1]=(f16)c.y; hc[2]=(f16)c.z; hc[3]=(f16)c.w;
    hd[0]=(f16)d.x; hd[1]=(f16)d.y; hd[2]=(f16)d.z; hd[3]=(f16)d.w;
    *(f16x4*)(w16 + i)            = ha;
    *(f16x4*)(w16 + 65536 + i)    = hb;
    *(f16x4*)(w16 + 131072 + i)   = hc;
    *(f16x4*)(w16 + 196608 + i)   = hd;
}

// ---------------------------------------------------------------------------
// mask_scan v2: per batch, BOTH compactions.
//  posm[n] = bg (mask==0) compact index or -1; posf[n] = fg (mask==1) compact
//  index or -1; cnts = {F_b, F_f}. Written into the SLOT's plane-0 tail.
// ---------------------------------------------------------------------------
__global__ __launch_bounds__(256) void mask_scan_kernel(
    const float* __restrict__ mask, f16* __restrict__ wsh, int b0)
{
    const int slot = blockIdx.x;
    const int b = b0 + slot;
    const int t = threadIdx.x;
    const int lane = t & 63, w = t >> 6;
    __shared__ int wsum0[4], wsum1[4];
    const float* mp = mask + (size_t)b * NN;
    f16* base = wsh + (size_t)slot * 4 * NM;
    int* pm = (int*)(base + OFF_POSM);
    int* pf = (int*)(base + OFF_POSF);
    int* cn = (int*)(base + OFF_CNT);

    int loc0[16], loc1[16], c0 = 0, c1 = 0;
    float mv[16];
#pragma unroll
    for (int i = 0; i < 16; ++i) {
        mv[i] = mp[t * 16 + i];
        loc0[i] = c0; loc1[i] = c1;
        if (mv[i] == 0.0f) ++c0; else ++c1;
    }
    int i0 = c0, i1 = c1;
#pragma unroll
    for (int d = 1; d < 64; d <<= 1) {
        int v0 = __shfl_up(i0, d, 64);
        int v1 = __shfl_up(i1, d, 64);
        if (lane >= d) { i0 += v0; i1 += v1; }
    }
    if (lane == 63) { wsum0[w] = i0; wsum1[w] = i1; }
    int e0 = i0 - c0, e1 = i1 - c1;
    __syncthreads();
    int s0 = e0, s1 = e1;
    for (int i = 0; i < w; ++i) { s0 += wsum0[i]; s1 += wsum1[i]; }
#pragma unroll
    for (int i = 0; i < 16; ++i) {
        pm[t * 16 + i] = (mv[i] == 0.0f) ? (s0 + loc0[i]) : -1;
        pf[t * 16 + i] = (mv[i] != 0.0f) ? (s1 + loc1[i]) : -1;
    }
    if (t == 0) {
        cn[0] = wsum0[0] + wsum0[1] + wsum0[2] + wsum0[3];
        cn[1] = wsum1[0] + wsum1[1] + wsum1[2] + wsum1[3];
    }
}

// ---------------------------------------------------------------------------
// proj_fused v3: q compacted to fg rows (posf scatter) + bq row at q[F_f] +
// q tail zeroed. k/v compacted (posm). (unchanged from R13/R14)
// ---------------------------------------------------------------------------
__global__ __launch_bounds__(512, 4) void proj_fused_kernel(
    const float* __restrict__ x, const float* __restrict__ mask,
    const f16* __restrict__ w16, const float* __restrict__ bq,
    const float* __restrict__ bk, const float* __restrict__ bv,
    f16* __restrict__ wsh, int b0)
{
    __shared__ f16x8 xf[2048];   // 32 KB, (x*m) fragment-major
    __shared__ f16x8 xb[2048];   // 32 KB, (x*(1-m))

    const int t = threadIdx.x;
    const int lane = t & 63, w = t >> 6;          // w in [0,8)
    const int l16 = lane & 15, quad = lane >> 4;
    const int slot = blockIdx.x;
    const int b = b0 + slot;
    const int n0 = blockIdx.y * 64;
    const float* xp = x + (size_t)b * NM;
    f16* base = wsh + (size_t)slot * 4 * NM;
    const int* pom = (const int*)(base + OFF_POSM);
    const int* pof = (const int*)(base + OFF_POSF);
    const int* cn  = (const int*)(base + OFF_CNT);

    float mf  = mask[(size_t)b * NN + n0 + lane];
    float mbk = 1.0f - mf;
#pragma unroll
    for (int i = 0; i < 4; ++i) {                 // 8 waves x 4 groups = 256 c
        int cb = w * 4 + i;
        const float* col = xp + (size_t)cb * 8 * NN + n0 + lane;
        f16x8 vf, vb;
#pragma unroll
        for (int u = 0; u < 8; ++u) {
            float xv = col[(size_t)u * NN];
            vf[u] = (f16)(xv * mf);
            vb[u] = (f16)(xv * mbk);
        }
        int unit = ((cb >> 2) * 4 + (lane >> 4)) * 64 + (cb & 3) * 16 + (lane & 15);
        xf[unit] = vf;
        xb[unit] = vb;
    }
    __syncthreads();

#pragma unroll
    for (int pr = 0; pr < 3; ++pr) {              // 8 waves x 3 pairs = 48 jobs
        int j0  = w * 6 + pr * 2;
        int p   = j0 >> 4;
        int oc0 = j0 & 15;
        const f16* Wp     = w16 + (size_t)p * 65536;
        const float* bias = (p == 0) ? bq : (p == 1) ? bk : bv;
        const f16x8* bt   = (p == 0) ? xf : xb;

        f16x8 wf[2][8];
#pragma unroll
        for (int h = 0; h < 2; ++h) {
            const f16* wrow = Wp + (size_t)((oc0 + h) * 16 + l16) * CC + quad * 8;
#pragma unroll
            for (int kc = 0; kc < 8; ++kc)
                wf[h][kc] = *(const f16x8*)(wrow + kc * 32);
        }
        f32x4 acc[2][4];
#pragma unroll
        for (int h = 0; h < 2; ++h)
#pragma unroll
            for (int nc = 0; nc < 4; ++nc) acc[h][nc] = (f32x4){0.f, 0.f, 0.f, 0.f};
#pragma unroll
        for (int nc = 0; nc < 4; ++nc)
#pragma unroll
            for (int kc = 0; kc < 8; ++kc) {
                f16x8 bf = bt[(kc * 4 + nc) * 64 + lane];
                acc[0][nc] = __builtin_amdgcn_mfma_f32_16x16x32_f16(wf[0][kc], bf, acc[0][nc], 0, 0, 0);
                acc[1][nc] = __builtin_amdgcn_mfma_f32_16x16x32_f16(wf[1][kc], bf, acc[1][nc], 0, 0, 0);
            }
#pragma unroll
        for (int h = 0; h < 2; ++h) {
            int oc = oc0 + h;
            float bvv[4];
#pragma unroll
            for (int r = 0; r < 4; ++r) bvv[r] = bias[oc * 16 + quad * 4 + r];
            if (p == 2) {                        // v [C][M] column-scatter (bg)
                f16* vpl = base + 2 * NM;
#pragma unroll
                for (int nc = 0; nc < 4; ++nc) {
                    int cp = pom[n0 + nc * 16 + l16];
                    if (cp >= 0) {
#pragma unroll
                        for (int r = 0; r < 4; ++r)
                            vpl[(size_t)(oc * 16 + quad * 4 + r) * NN + cp] =
                                (f16)(acc[h][nc][r] + bvv[r]);
                    }
                }
            } else if (p == 1) {                 // k [M][C] row-scatter (bg)
                f16* kpl = base + NM;
#pragma unroll
                for (int nc = 0; nc < 4; ++nc) {
                    int cp = pom[n0 + nc * 16 + l16];
                    if (cp >= 0) {
                        f16x4 pk;
#pragma unroll
                        for (int r = 0; r < 4; ++r) pk[r] = (f16)(acc[h][nc][r] + bvv[r]);
                        *(f16x4*)(kpl + (size_t)cp * CC + oc * 16 + quad * 4) = pk;
                    }
                }
            } else {                             // q [Qc][C] row-scatter (fg)
#pragma unroll
                for (int nc = 0; nc < 4; ++nc) {
                    int cp = pof[n0 + nc * 16 + l16];
                    if (cp >= 0) {
                        f16x4 pk;
#pragma unroll
                        for (int r = 0; r < 4; ++r) pk[r] = (f16)(acc[h][nc][r] + bvv[r]);
                        *(f16x4*)(base + (size_t)cp * CC + oc * 16 + quad * 4) = pk;
                    }
                }
            }
        }
    }

    // pad/aux section, once per slot
    if (blockIdx.y == 0) {
        int Fb = cn[0], Ff = cn[1];
        f16x8 z8;
#pragma unroll
        for (int i = 0; i < 8; ++i) z8[i] = (f16)0.0f;
        {
            int Mp = (Fb + 31) & ~31;
            int pad = Mp - Fb;
            if (pad > 0) {
                f16* kpl = base + NM;
                f16* vpl = base + 2 * NM;
                for (int idx = t; idx < pad * 32; idx += 512)
                    *(f16x8*)(kpl + (size_t)(Fb + idx / 32) * CC + (idx & 31) * 8) = z8;
                for (int idx = t; idx < pad * CC; idx += 512)
                    vpl[(size_t)(idx / pad) * NN + Fb + (idx % pad)] = (f16)0.0f;
            }
        }
        // bq row at q[Ff] (the shared bg query), f16
        for (int c = t; c < CC; c += 512)
            base[(size_t)Ff * CC + c] = (f16)bq[c];
        // zero q tail rows Ff+1 .. ceil64(Ff+1)-1
        {
            int qe = (Ff + 64) & ~63;
            int nz = qe - (Ff + 1);
            for (int idx = t; idx < nz * 32; idx += 512)
                *(f16x8*)(base + (size_t)(Ff + 1 + idx / 32) * CC + (idx & 31) * 8) = z8;
        }
    }
}

// ---------------------------------------------------------------------------
// flash v12: R13's 4-wave/64-row per-block math, SINGLE-buffered K/V LDS.
//   R14 post-mortem: makespan = (max blocks/CU) x block latency; dbuf LDS
//   (70 KB) capped residency at 2 blocks/CU, so any block count in (256,512]
//   left 2x straggler CUs. Single buffer: 16K + 16K + 5K = 38 KB -> 4
//   blocks/CU; all 576 blocks (36 qtiles x 2 m-halves x 8 slots) co-resident
//   from t=0 -> no rounds, no stragglers. The per-iter exposed GLD16 latency
//   (vmcnt(0) each iter, no prefetch) is hidden by the 3-4 co-resident
//   independent blocks per CU. __launch_bounds__(256,4) caps VGPR at 128.
// ---------------------------------------------------------------------------
__global__ __launch_bounds__(256, 4) void flash_kernel(
    f16* __restrict__ wsh, const float* __restrict__ bk,
    const float* __restrict__ bv, int b0)
{
    __shared__ f16x8 klds[1024];       // 16 KB : 32m x 256c fragment-major
    __shared__ f16x8 vlds[1024];       // 16 KB : [c][m] fragment-major
    __shared__ f16 pbuf[4][16 * 40];   // 5 KB, per-wave P tile, stride 40

    const int t    = threadIdx.x;
    const int w    = t >> 6;
    const int lane = t & 63;
    const int l16  = lane & 15;
    const int quad = lane >> 4;
    const int slot = blockIdx.x;
    const int n0   = (blockIdx.y >> 1) * 64;  // compacted q-row tile base
    const int z    = blockIdx.y & 1;          // m-half

    f16* base = wsh + (size_t)slot * 4 * NM;
    const int* cn = (const int*)(base + OFF_CNT);
    const int Fb = cn[0], Ff = cn[1];
    if (n0 > Ff) return;               // tile entirely beyond the bq row

    const f16* qt = base;              // [Qc][C] compacted (+bq row Ff)
    const f16* kt = base + NM;         // [M][C] compacted bg
    const f16* vp = base + 2 * NM;     // [C][M] compacted bg

    const int nt  = (Fb + 31) >> 5;
    const int h   = (nt + 1) >> 1;
    const int mt0 = z ? h : 0;
    const int mt1 = z ? nt : h;

    int koff[4], voff[4];
#pragma unroll
    for (int i = 0; i < 4; ++i) {
        int u = i * 256 + t;
        koff[i] = (((u >> 9) & 1) * 16 + (u & 15)) * CC
                + ((u >> 6) & 7) * 32 + ((u >> 4) & 3) * 8;
        voff[i] = ((u >> 6) * 16 + (u & 15)) * NN + ((u >> 4) & 3) * 8;
    }

#define ISSUE(m0_) do {                                                         \
    _Pragma("unroll")                                                           \
    for (int i_ = 0; i_ < 4; ++i_)                                              \
        GLD16(kt + (size_t)(m0_) * CC + koff[i_],                               \
              (f16*)&klds[i_ * 256 + w * 64]);                                  \
    _Pragma("unroll")                                                           \
    for (int i_ = 0; i_ < 4; ++i_)                                              \
        GLD16(vp + (size_t)(m0_) + voff[i_],                                    \
              (f16*)&vlds[i_ * 256 + w * 64]);                                  \
} while (0)

    // Q fragments for this wave's 16 compacted rows
    const int nrow = n0 + w * 16 + l16;
    f16x8 qf[8];
#pragma unroll
    for (int kc = 0; kc < 8; ++kc)
        qf[kc] = *(const f16x8*)(qt + (size_t)nrow * CC + kc * 32 + quad * 8);
#pragma unroll
    for (int kc = 0; kc < 8; ++kc)
        asm volatile("" :: "v"(qf[kc]));
    // drain all prior VMEM so staging is the only thing vmcnt counts
    asm volatile("s_waitcnt vmcnt(0)" ::: "memory");

    f32x4 oacc[17];                    // [0..15]: O cols; [16]: row-sum L
#pragma unroll
    for (int i = 0; i < 17; ++i) oacc[i] = (f32x4){0.f, 0.f, 0.f, 0.f};
    float M[4] = {-3.0e38f, -3.0e38f, -3.0e38f, -3.0e38f};

    f16* pw = &pbuf[w][0];
    f16x8 ones;
#pragma unroll
    for (int i = 0; i < 8; ++i) ones[i] = (f16)1.0f;

    for (int it = mt0; it < mt1; ++it) {
        ISSUE(it * 32);
        // my wave's 8 loads done; barrier joins all waves -> tile fully ready
        asm volatile("s_waitcnt vmcnt(0)" ::: "memory");
        __builtin_amdgcn_s_barrier();
        asm volatile("" ::: "memory");

        // ---- QK^T: 16 rows x 32 m ----
        f32x4 s[2];
        s[0] = (f32x4){0.f, 0.f, 0.f, 0.f};
        s[1] = (f32x4){0.f, 0.f, 0.f, 0.f};
        __builtin_amdgcn_s_setprio(1);
#pragma unroll
        for (int kc = 0; kc < 8; ++kc) {
            f16x8 k0 = klds[kc * 64 + lane];
            f16x8 k1 = klds[(8 + kc) * 64 + lane];
            s[0] = __builtin_amdgcn_mfma_f32_16x16x32_f16(qf[kc], k0, s[0], 0, 0, 0);
            s[1] = __builtin_amdgcn_mfma_f32_16x16x32_f16(qf[kc], k1, s[1], 0, 0, 0);
        }
        __builtin_amdgcn_s_setprio(0);

        // ---- tail mask: columns beyond F_b get exactly zero weight ----
        if (((it + 1) << 5) > Fb) {
#pragma unroll
            for (int ms = 0; ms < 2; ++ms)
                if (it * 32 + ms * 16 + l16 >= Fb) {
#pragma unroll
                    for (int r = 0; r < 4; ++r) s[ms][r] = -3.0e38f;
                }
        }

        // ---- defer-max (T13): rescale only when tile max exceeds M+8 ----
        bool up = false;
#pragma unroll
        for (int ms = 0; ms < 2; ++ms)
#pragma unroll
            for (int r = 0; r < 4; ++r) up |= (s[ms][r] > M[r] + 8.0f);
        if (__any(up)) {
            float alpha[4];
#pragma unroll
            for (int r = 0; r < 4; ++r) {
                float tm = fmaxf(s[0][r], s[1][r]);
                tm = fmaxf(tm, __shfl_xor(tm, 1, 64));
                tm = fmaxf(tm, __shfl_xor(tm, 2, 64));
                tm = fmaxf(tm, __shfl_xor(tm, 4, 64));
                tm = fmaxf(tm, __shfl_xor(tm, 8, 64));
                float Mn = fmaxf(M[r], tm);
                alpha[r] = __expf(M[r] - Mn);
                M[r] = Mn;
            }
#pragma unroll
            for (int cs = 0; cs < 17; ++cs)
#pragma unroll
                for (int r = 0; r < 4; ++r) oacc[cs][r] *= alpha[r];
        }
        // P = exp(s - M)  (bounded by e^8), write per-wave P tile
#pragma unroll
        for (int ms = 0; ms < 2; ++ms)
#pragma unroll
            for (int r = 0; r < 4; ++r)
                pw[(quad * 4 + r) * 40 + ms * 16 + l16] = (f16)__expf(s[ms][r] - M[r]);
        asm volatile("s_waitcnt lgkmcnt(0)" ::: "memory");
        f16x8 pf = *(const f16x8*)(pw + l16 * 40 + quad * 8);

        // ---- PV: 16 rows x 256 c (+ L column) ----
        __builtin_amdgcn_s_setprio(1);
#pragma unroll
        for (int cs = 0; cs < 16; ++cs) {
            f16x8 vf = vlds[cs * 64 + lane];
            oacc[cs] = __builtin_amdgcn_mfma_f32_16x16x32_f16(pf, vf, oacc[cs], 0, 0, 0);
        }
        oacc[16] = __builtin_amdgcn_mfma_f32_16x16x32_f16(pf, ones, oacc[16], 0, 0, 0);
        __builtin_amdgcn_s_setprio(0);

        // all waves done reading klds/vlds before next iter's ISSUE overwrites
        asm volatile("" ::: "memory");
        __builtin_amdgcn_s_barrier();
    }
    asm volatile("s_waitcnt vmcnt(0)" ::: "memory");

    // ---- analytic fg column (z=0 only): score q.bk, weight F_f, value bv ----
    if (z == 0) {
        float cnn = 0.f;
#pragma unroll
        for (int kc = 0; kc < 8; ++kc) {
            const float* bkp = bk + kc * 32 + quad * 8;
#pragma unroll
            for (int j = 0; j < 8; ++j)
                cnn += (float)qf[kc][j] * bkp[j];
        }
        cnn += __shfl_xor(cnn, 16, 64);
        cnn += __shfl_xor(cnn, 32, 64);
        const float Ffw = (float)Ff;      // fg column multiplicity = F_f
        float aw[4], wv[4];
#pragma unroll
        for (int r = 0; r < 4; ++r) {
            float cr = __shfl(cnn, quad * 4 + r, 64);
            float Mn = fmaxf(M[r], cr);
            aw[r] = __expf(M[r] - Mn);
            wv[r] = Ffw * __expf(cr - Mn);
            M[r] = Mn;
        }
#pragma unroll
        for (int cs = 0; cs < 16; ++cs) {
            float bvc = bv[cs * 16 + l16];
#pragma unroll
            for (int r = 0; r < 4; ++r)
                oacc[cs][r] = oacc[cs][r] * aw[r] + wv[r] * bvc;
        }
#pragma unroll
        for (int r = 0; r < 4; ++r)
            oacc[16][r] = oacc[16][r] * aw[r] + wv[r];
    }

    // ---- partial epilogue: write O/L (f16), L, M for this half ----
    float inv[4];
#pragma unroll
    for (int r = 0; r < 4; ++r) {
        float Lr = oacc[16][r];
        inv[r] = (Lr > 0.f) ? 1.0f / Lr : 0.f;   // empty half -> store 0, w=0
    }
#pragma unroll
    for (int r = 0; r < 4; ++r) {
        int row = n0 + w * 16 + quad * 4 + r;
        f16* pp = (row < 2048)
                ? base + 3 * NM + (size_t)z * PMAIN + (size_t)row * 256
                : base + OFF_OVF + (size_t)z * 65536 + (size_t)(row - 2048) * 256;
#pragma unroll
        for (int cs = 0; cs < 16; ++cs)
            pp[cs * 16 + l16] = (f16)(oacc[cs][r] * inv[r]);
    }
    if (l16 == 0) {
        float* LMw = (float*)(base + OFF_LM);
#pragma unroll
        for (int r = 0; r < 4; ++r) {
            int row = n0 + w * 16 + quad * 4 + r;
            LMw[((size_t)z * QCAP + row) * 2 + 0] = oacc[16][r];
            LMw[((size_t)z * QCAP + row) * 2 + 1] = M[r];
        }
    }
#undef ISSUE
}

// ---------------------------------------------------------------------------
// combine: grid (nb, 64) over ORIGINAL n-tiles (2 blocks/CU, coalesced out).
// Per row: crow = posf[n] (fg) or F_f (bg -> shared bq row). Gather both
// halves' partials, merge by softmax weights, stage into the verified
// fragment-major LDS layout, then the verbatim final MFMA phase.
// ---------------------------------------------------------------------------
__global__ __launch_bounds__(256, 2) void combine_kernel(
    const f16* __restrict__ wsh, const float* __restrict__ bo,
    const float* __restrict__ x, const float* __restrict__ gamma,
    float* __restrict__ outall, int b0)
{
    __shared__ f16x8 ot[2048];   // 32 KB merged-O tile, fragment-major

    const int t = threadIdx.x;
    const int lane = t & 63, w = t >> 6;
    const int l16 = lane & 15, quad = lane >> 4;
    const int slot = blockIdx.x;
    const int b = b0 + slot;
    const int n0 = blockIdx.y * 64;

    const f16* base = wsh + (size_t)slot * 4 * NM;
    const int* pof = (const int*)(base + OFF_POSF);
    const int* cn  = (const int*)(base + OFF_CNT);
    const int Ff = cn[1];
    const float* LMp = (const float*)(base + OFF_LM);
    const f16* wo16 = wsh + OFF_W16 + (size_t)3 * 65536;

#pragma unroll
    for (int i = 0; i < 8; ++i) {
        int u = i * 256 + t;
        int ul16 = u & 15, uq = (u >> 4) & 3, unc = (u >> 6) & 3, ukc = u >> 8;
        int orign = n0 + unc * 16 + ul16;
        int pfv = pof[orign];
        int crow = (pfv >= 0) ? pfv : Ff;
        int c0 = ukc * 32 + uq * 8;
        const f16* p0 = (crow < 2048)
                      ? base + 3 * NM + (size_t)crow * 256
                      : base + OFF_OVF + (size_t)(crow - 2048) * 256;
        const f16* p1 = (crow < 2048)
                      ? base + 3 * NM + PMAIN + (size_t)crow * 256
                      : base + OFF_OVF + 65536 + (size_t)(crow - 2048) * 256;
        f16x8 o0 = *(const f16x8*)(p0 + c0);
        f16x8 o1 = *(const f16x8*)(p1 + c0);
        float L0 = LMp[(size_t)crow * 2], M0 = LMp[(size_t)crow * 2 + 1];
        float L1 = LMp[((size_t)QCAP + crow) * 2], M1 = LMp[((size_t)QCAP + crow) * 2 + 1];
        float Mx = fmaxf(M0, M1);
        float w0 = L0 * __expf(M0 - Mx);
        float w1 = L1 * __expf(M1 - Mx);
        float inv = 1.0f / (w0 + w1);
        f16x8 om;
#pragma unroll
        for (int j = 0; j < 8; ++j)
            om[j] = (f16)((w0 * (float)o0[j] + w1 * (float)o1[j]) * inv);
        ot[u] = om;
    }
    __syncthreads();

    // final MFMA phase (verbatim from the verified final_kernel)
    const float* xp = x + (size_t)b * NM;
    float* outp = outall + (size_t)b * NM;
    float g = gamma[0];
#pragma unroll
    for (int pr = 0; pr < 2; ++pr) {
        int oc0 = w * 4 + pr * 2;
        f16x8 wf[2][8];
#pragma unroll
        for (int h = 0; h < 2; ++h) {
            const f16* wrow = wo16 + (size_t)((oc0 + h) * 16 + l16) * CC + quad * 8;
#pragma unroll
            for (int kc = 0; kc < 8; ++kc)
                wf[h][kc] = *(const f16x8*)(wrow + kc * 32);
        }
        f32x4 acc[2][4];
#pragma unroll
        for (int h = 0; h < 2; ++h)
#pragma unroll
            for (int nc = 0; nc < 4; ++nc) acc[h][nc] = (f32x4){0.f, 0.f, 0.f, 0.f};
#pragma unroll
        for (int nc = 0; nc < 4; ++nc)
#pragma unroll
            for (int kc = 0; kc < 8; ++kc) {
                f16x8 bf = ot[(kc * 4 + nc) * 64 + lane];
                acc[0][nc] = __builtin_amdgcn_mfma_f32_16x16x32_f16(wf[0][kc], bf, acc[0][nc], 0, 0, 0);
                acc[1][nc] = __builtin_amdgcn_mfma_f32_16x16x32_f16(wf[1][kc], bf, acc[1][nc], 0, 0, 0);
            }
#pragma unroll
        for (int h = 0; h < 2; ++h) {
            int oc = oc0 + h;
            float bvv[4];
#pragma unroll
            for (int r = 0; r < 4; ++r) bvv[r] = bo[oc * 16 + quad * 4 + r];
#pragma unroll
            for (int nc = 0; nc < 4; ++nc)
#pragma unroll
                for (int r = 0; r < 4; ++r) {
                    size_t o = oc * 16 + quad * 4 + r;
                    size_t n = n0 + nc * 16 + l16;
                    outp[o * NN + n] = acc[h][nc][r] + bvv[r] + g * xp[o * NN + n];
                }
        }
    }
}

// ---------------------------------------------------------------------------
__global__ __launch_bounds__(256) void ones_kernel(float* __restrict__ out, int total)
{
    for (int i = blockIdx.x * 256 + threadIdx.x; i < total; i += gridDim.x * 256)
        out[i] = 1.0f;
}

// ---------------------------------------------------------------------------
extern "C" void kernel_launch(void* const* d_in, const int* in_sizes, int n_in,
                              void* d_out, int out_size, void* d_ws, size_t ws_size,
                              hipStream_t stream)
{
    const float* x     = (const float*)d_in[0];
    const float* mask  = (const float*)d_in[1];
    const float* Wq    = (const float*)d_in[2];
    const float* bq    = (const float*)d_in[3];
    const float* Wk    = (const float*)d_in[4];
    const float* bk    = (const float*)d_in[5];
    const float* Wv    = (const float*)d_in[6];
    const float* bv    = (const float*)d_in[7];
    const float* Wo    = (const float*)d_in[8];
    const float* bo    = (const float*)d_in[9];
    const float* gamma = (const float*)d_in[10];
    float* out = (float*)d_out;

    const size_t slot_bytes = 4 * NM * sizeof(f16);   // 8 MiB
    f16* wsh = (f16*)d_ws;
    int nb = (int)(ws_size / slot_bytes);
    if (nb < 1) {
        ones_kernel<<<2048, 256, 0, stream>>>(out, out_size);
        return;
    }
    if (nb > NB) nb = NB;

    f16* w16 = wsh + OFF_W16;          // slot 0 plane-0 tail
    wprep_kernel<<<64, 256, 0, stream>>>(Wq, Wk, Wv, Wo, w16);

    for (int b0 = 0; b0 < NB; b0 += nb) {
        int nbc = NB - b0; if (nbc > nb) nbc = nb;
        mask_scan_kernel<<<nbc, 256, 0, stream>>>(mask, wsh, b0);
        dim3 gP(nbc, NN / 64);                 // slot-major: slot -> XCD
        dim3 gF(nbc, (QCAP / 64) * 2);         // 36 q-tiles x 2 m-halves = 576 blocks
        dim3 gC(nbc, NN / 64);
        proj_fused_kernel<<<gP, 512, 0, stream>>>(x, mask, w16, bq, bk, bv, wsh, b0);
        flash_kernel<<<gF, 256, 0, stream>>>(wsh, bk, bv, b0);
        combine_kernel<<<gC, 256, 0, stream>>>(wsh, bo, x, gamma, out, b0);
    }
}

// Round 16
// 278.772 us; speedup vs baseline: 1.0761x; 1.0761x over previous
//
#include <hip/hip_runtime.h>

#define CC 256
#define NN 4096
#define NB 8
#define NM ((size_t)CC * NN)   // 1M f16 elems per plane

// per-slot plane-0 tail layout (f16-unit offsets within the slot's plane 0).
#define OFF_OVF   589824   // partial rows 2048..2303:  + z*65536 + (row-2048)*256
#define OFF_LM    720896   // float[(z*2304 + row)*2] = {L, M}
#define OFF_POSM  739328   // int[4096] bg compact index or -1
#define OFF_POSF  747520   // int[4096] fg compact index or -1
#define OFF_CNT   755712   // int[2] = {F_b, F_f}
#define OFF_W16   755776   // slot 0 only: f16[4*65536] = Wq,Wk,Wv,Wo
#define PMAIN     524288   // plane 3: + z*PMAIN + row*256, rows 0..2047
#define QCAP      2304     // max compacted q rows (F_f+1; 8 sigma bound)

typedef _Float16 f16;
typedef f16 f16x4 __attribute__((ext_vector_type(4)));
typedef f16 f16x8 __attribute__((ext_vector_type(8)));
typedef float f32x4 __attribute__((ext_vector_type(4)));
typedef unsigned int u32;

// ---------------------------------------------------------------------------
// wprep: one-time f32->f16 conversion of Wq/Wk/Wv/Wo into slot-0 plane-0 tail.
// ---------------------------------------------------------------------------
__global__ __launch_bounds__(256) void wprep_kernel(
    const float* __restrict__ Wq, const float* __restrict__ Wk,
    const float* __restrict__ Wv, const float* __restrict__ Wo,
    f16* __restrict__ w16)
{
    int i = (blockIdx.x * 256 + threadIdx.x) * 4;   // grid 64 -> covers 65536
    float4 a = *(const float4*)(Wq + i);
    float4 b = *(const float4*)(Wk + i);
    float4 c = *(const float4*)(Wv + i);
    float4 d = *(const float4*)(Wo + i);
    f16x4 ha, hb, hc, hd;
    ha[0]=(f16)a.x; ha[1]=(f16)a.y; ha[2]=(f16)a.z; ha[3]=(f16)a.w;
    hb[0]=(f16)b.x; hb[1]=(f16)b.y; hb[2]=(f16)b.z; hb[3]=(f16)b.w;
    hc[0]=(f16)c.x; hc[1]=(f16)c.y; hc[2]=(f16)c.z; hc[3]=(f16)c.w;
    hd[0]=(f16)d.x; hd[1]=(f16)d.y; hd[2]=(f16)d.z; hd[3]=(f16)d.w;
    *(f16x4*)(w16 + i)            = ha;
    *(f16x4*)(w16 + 65536 + i)    = hb;
    *(f16x4*)(w16 + 131072 + i)   = hc;
    *(f16x4*)(w16 + 196608 + i)   = hd;
}

// ---------------------------------------------------------------------------
// mask_scan v2: per batch, BOTH compactions.
//  posm[n] = bg (mask==0) compact index or -1; posf[n] = fg (mask==1) compact
//  index or -1; cnts = {F_b, F_f}. Written into the SLOT's plane-0 tail.
// ---------------------------------------------------------------------------
__global__ __launch_bounds__(256) void mask_scan_kernel(
    const float* __restrict__ mask, f16* __restrict__ wsh, int b0)
{
    const int slot = blockIdx.x;
    const int b = b0 + slot;
    const int t = threadIdx.x;
    const int lane = t & 63, w = t >> 6;
    __shared__ int wsum0[4], wsum1[4];
    const float* mp = mask + (size_t)b * NN;
    f16* base = wsh + (size_t)slot * 4 * NM;
    int* pm = (int*)(base + OFF_POSM);
    int* pf = (int*)(base + OFF_POSF);
    int* cn = (int*)(base + OFF_CNT);

    int loc0[16], loc1[16], c0 = 0, c1 = 0;
    float mv[16];
#pragma unroll
    for (int i = 0; i < 16; ++i) {
        mv[i] = mp[t * 16 + i];
        loc0[i] = c0; loc1[i] = c1;
        if (mv[i] == 0.0f) ++c0; else ++c1;
    }
    int i0 = c0, i1 = c1;
#pragma unroll
    for (int d = 1; d < 64; d <<= 1) {
        int v0 = __shfl_up(i0, d, 64);
        int v1 = __shfl_up(i1, d, 64);
        if (lane >= d) { i0 += v0; i1 += v1; }
    }
    if (lane == 63) { wsum0[w] = i0; wsum1[w] = i1; }
    int e0 = i0 - c0, e1 = i1 - c1;
    __syncthreads();
    int s0 = e0, s1 = e1;
    for (int i = 0; i < w; ++i) { s0 += wsum0[i]; s1 += wsum1[i]; }
#pragma unroll
    for (int i = 0; i < 16; ++i) {
        pm[t * 16 + i] = (mv[i] == 0.0f) ? (s0 + loc0[i]) : -1;
        pf[t * 16 + i] = (mv[i] != 0.0f) ? (s1 + loc1[i]) : -1;
    }
    if (t == 0) {
        cn[0] = wsum0[0] + wsum0[1] + wsum0[2] + wsum0[3];
        cn[1] = wsum1[0] + wsum1[1] + wsum1[2] + wsum1[3];
    }
}

// ---------------------------------------------------------------------------
// proj_fused v3: q compacted to fg rows (posf scatter) + bq row at q[F_f] +
// q tail zeroed. k/v compacted (posm). (unchanged from R13/R14/R15)
// ---------------------------------------------------------------------------
__global__ __launch_bounds__(512, 4) void proj_fused_kernel(
    const float* __restrict__ x, const float* __restrict__ mask,
    const f16* __restrict__ w16, const float* __restrict__ bq,
    const float* __restrict__ bk, const float* __restrict__ bv,
    f16* __restrict__ wsh, int b0)
{
    __shared__ f16x8 xf[2048];   // 32 KB, (x*m) fragment-major
    __shared__ f16x8 xb[2048];   // 32 KB, (x*(1-m))

    const int t = threadIdx.x;
    const int lane = t & 63, w = t >> 6;          // w in [0,8)
    const int l16 = lane & 15, quad = lane >> 4;
    const int slot = blockIdx.x;
    const int b = b0 + slot;
    const int n0 = blockIdx.y * 64;
    const float* xp = x + (size_t)b * NM;
    f16* base = wsh + (size_t)slot * 4 * NM;
    const int* pom = (const int*)(base + OFF_POSM);
    const int* pof = (const int*)(base + OFF_POSF);
    const int* cn  = (const int*)(base + OFF_CNT);

    float mf  = mask[(size_t)b * NN + n0 + lane];
    float mbk = 1.0f - mf;
#pragma unroll
    for (int i = 0; i < 4; ++i) {                 // 8 waves x 4 groups = 256 c
        int cb = w * 4 + i;
        const float* col = xp + (size_t)cb * 8 * NN + n0 + lane;
        f16x8 vf, vb;
#pragma unroll
        for (int u = 0; u < 8; ++u) {
            float xv = col[(size_t)u * NN];
            vf[u] = (f16)(xv * mf);
            vb[u] = (f16)(xv * mbk);
        }
        int unit = ((cb >> 2) * 4 + (lane >> 4)) * 64 + (cb & 3) * 16 + (lane & 15);
        xf[unit] = vf;
        xb[unit] = vb;
    }
    __syncthreads();

#pragma unroll
    for (int pr = 0; pr < 3; ++pr) {              // 8 waves x 3 pairs = 48 jobs
        int j0  = w * 6 + pr * 2;
        int p   = j0 >> 4;
        int oc0 = j0 & 15;
        const f16* Wp     = w16 + (size_t)p * 65536;
        const float* bias = (p == 0) ? bq : (p == 1) ? bk : bv;
        const f16x8* bt   = (p == 0) ? xf : xb;

        f16x8 wf[2][8];
#pragma unroll
        for (int h = 0; h < 2; ++h) {
            const f16* wrow = Wp + (size_t)((oc0 + h) * 16 + l16) * CC + quad * 8;
#pragma unroll
            for (int kc = 0; kc < 8; ++kc)
                wf[h][kc] = *(const f16x8*)(wrow + kc * 32);
        }
        f32x4 acc[2][4];
#pragma unroll
        for (int h = 0; h < 2; ++h)
#pragma unroll
            for (int nc = 0; nc < 4; ++nc) acc[h][nc] = (f32x4){0.f, 0.f, 0.f, 0.f};
#pragma unroll
        for (int nc = 0; nc < 4; ++nc)
#pragma unroll
            for (int kc = 0; kc < 8; ++kc) {
                f16x8 bf = bt[(kc * 4 + nc) * 64 + lane];
                acc[0][nc] = __builtin_amdgcn_mfma_f32_16x16x32_f16(wf[0][kc], bf, acc[0][nc], 0, 0, 0);
                acc[1][nc] = __builtin_amdgcn_mfma_f32_16x16x32_f16(wf[1][kc], bf, acc[1][nc], 0, 0, 0);
            }
#pragma unroll
        for (int h = 0; h < 2; ++h) {
            int oc = oc0 + h;
            float bvv[4];
#pragma unroll
            for (int r = 0; r < 4; ++r) bvv[r] = bias[oc * 16 + quad * 4 + r];
            if (p == 2) {                        // v [C][M] column-scatter (bg)
                f16* vpl = base + 2 * NM;
#pragma unroll
                for (int nc = 0; nc < 4; ++nc) {
                    int cp = pom[n0 + nc * 16 + l16];
                    if (cp >= 0) {
#pragma unroll
                        for (int r = 0; r < 4; ++r)
                            vpl[(size_t)(oc * 16 + quad * 4 + r) * NN + cp] =
                                (f16)(acc[h][nc][r] + bvv[r]);
                    }
                }
            } else if (p == 1) {                 // k [M][C] row-scatter (bg)
                f16* kpl = base + NM;
#pragma unroll
                for (int nc = 0; nc < 4; ++nc) {
                    int cp = pom[n0 + nc * 16 + l16];
                    if (cp >= 0) {
                        f16x4 pk;
#pragma unroll
                        for (int r = 0; r < 4; ++r) pk[r] = (f16)(acc[h][nc][r] + bvv[r]);
                        *(f16x4*)(kpl + (size_t)cp * CC + oc * 16 + quad * 4) = pk;
                    }
                }
            } else {                             // q [Qc][C] row-scatter (fg)
#pragma unroll
                for (int nc = 0; nc < 4; ++nc) {
                    int cp = pof[n0 + nc * 16 + l16];
                    if (cp >= 0) {
                        f16x4 pk;
#pragma unroll
                        for (int r = 0; r < 4; ++r) pk[r] = (f16)(acc[h][nc][r] + bvv[r]);
                        *(f16x4*)(base + (size_t)cp * CC + oc * 16 + quad * 4) = pk;
                    }
                }
            }
        }
    }

    // pad/aux section, once per slot
    if (blockIdx.y == 0) {
        int Fb = cn[0], Ff = cn[1];
        f16x8 z8;
#pragma unroll
        for (int i = 0; i < 8; ++i) z8[i] = (f16)0.0f;
        {
            int Mp = (Fb + 31) & ~31;
            int pad = Mp - Fb;
            if (pad > 0) {
                f16* kpl = base + NM;
                f16* vpl = base + 2 * NM;
                for (int idx = t; idx < pad * 32; idx += 512)
                    *(f16x8*)(kpl + (size_t)(Fb + idx / 32) * CC + (idx & 31) * 8) = z8;
                for (int idx = t; idx < pad * CC; idx += 512)
                    vpl[(size_t)(idx / pad) * NN + Fb + (idx % pad)] = (f16)0.0f;
            }
        }
        // bq row at q[Ff] (the shared bg query), f16
        for (int c = t; c < CC; c += 512)
            base[(size_t)Ff * CC + c] = (f16)bq[c];
        // zero q tail rows Ff+1 .. ceil64(Ff+1)-1
        {
            int qe = (Ff + 64) & ~63;
            int nz = qe - (Ff + 1);
            for (int idx = t; idx < nz * 32; idx += 512)
                *(f16x8*)(base + (size_t)(Ff + 1 + idx / 32) * CC + (idx & 31) * 8) = z8;
        }
    }
}

// ---------------------------------------------------------------------------
// flash v13: R15's math (q+m compacted, defer-max, ones-column L, analytic fg
// column, partial O/L/M output) with REGISTER-STAGED PREFETCH into a SINGLE
// LDS buffer -- R0's verified loop skeleton:
//   regs -> ds_write -> __syncthreads -> issue next-tile global loads (regs)
//   -> compute (loads' latency hides under QK/softmax/PV) -> __syncthreads.
// R15 post-mortem: single-buffer + vmcnt(0) exposed full load latency per
// iter (~11k cyc/iter); prefetch existed only in the dbuf variants whose
// 70 KB LDS capped residency at 2 blocks/CU (straggler rounds for 576-block
// grids). This combines prefetch (R0/R9/R13-proven) with the 38 KB footprint
// (R15-proven): combined regs ~165 -> 3 blocks/CU capacity >= 2.25 grid
// density -> all 576 blocks co-resident AND latency-hidden. No inline-asm
// vmcnt counting anywhere (plain __syncthreads ordering, R0-verified).
// ---------------------------------------------------------------------------
__global__ __launch_bounds__(256, 2) void flash_kernel(
    f16* __restrict__ wsh, const float* __restrict__ bk,
    const float* __restrict__ bv, int b0)
{
    __shared__ f16x8 klds[1024];       // 16 KB : 32m x 256c fragment-major
    __shared__ f16x8 vlds[1024];       // 16 KB : [c][m] fragment-major
    __shared__ f16 pbuf[4][16 * 40];   // 5 KB, per-wave P tile, stride 40

    const int t    = threadIdx.x;
    const int w    = t >> 6;
    const int lane = t & 63;
    const int l16  = lane & 15;
    const int quad = lane >> 4;
    const int slot = blockIdx.x;
    const int n0   = (blockIdx.y >> 1) * 64;  // compacted q-row tile base
    const int z    = blockIdx.y & 1;          // m-half

    f16* base = wsh + (size_t)slot * 4 * NM;
    const int* cn = (const int*)(base + OFF_CNT);
    const int Fb = cn[0], Ff = cn[1];
    if (n0 > Ff) return;               // tile entirely beyond the bq row

    const f16* qt = base;              // [Qc][C] compacted (+bq row Ff)
    const f16* kt = base + NM;         // [M][C] compacted bg
    const f16* vp = base + 2 * NM;     // [C][M] compacted bg

    const int nt  = (Fb + 31) >> 5;
    const int h   = (nt + 1) >> 1;
    const int mt0 = z ? h : 0;
    const int mt1 = z ? nt : h;

    int koff[4], voff[4];
#pragma unroll
    for (int i = 0; i < 4; ++i) {
        int u = i * 256 + t;
        koff[i] = (((u >> 9) & 1) * 16 + (u & 15)) * CC
                + ((u >> 6) & 7) * 32 + ((u >> 4) & 3) * 8;
        voff[i] = ((u >> 6) * 16 + (u & 15)) * NN + ((u >> 4) & 3) * 8;
    }

    // Q fragments for this wave's 16 compacted rows
    const int nrow = n0 + w * 16 + l16;
    f16x8 qf[8];
#pragma unroll
    for (int kc = 0; kc < 8; ++kc)
        qf[kc] = *(const f16x8*)(qt + (size_t)nrow * CC + kc * 32 + quad * 8);

    f32x4 oacc[17];                    // [0..15]: O cols; [16]: row-sum L
#pragma unroll
    for (int i = 0; i < 17; ++i) oacc[i] = (f32x4){0.f, 0.f, 0.f, 0.f};
    float M[4] = {-3.0e38f, -3.0e38f, -3.0e38f, -3.0e38f};

    f16* pw = &pbuf[w][0];
    f16x8 ones;
#pragma unroll
    for (int i = 0; i < 8; ++i) ones[i] = (f16)1.0f;

    // prologue: stage first tile into registers
    f16x8 kreg[4], vreg[4];
    if (mt1 > mt0) {
#pragma unroll
        for (int i = 0; i < 4; ++i) {
            kreg[i] = *(const f16x8*)(kt + (size_t)(mt0 * 32) * CC + koff[i]);
            vreg[i] = *(const f16x8*)(vp + (size_t)(mt0 * 32) + voff[i]);
        }
    }

    for (int it = mt0; it < mt1; ++it) {
        // write staged regs to LDS (compiler waits the loads here)
#pragma unroll
        for (int i = 0; i < 4; ++i) {
            klds[i * 256 + t] = kreg[i];
            vlds[i * 256 + t] = vreg[i];
        }
        __syncthreads();
        // prefetch next tile into regs; latency hides under compute below
        if (it + 1 < mt1) {
#pragma unroll
            for (int i = 0; i < 4; ++i) {
                kreg[i] = *(const f16x8*)(kt + (size_t)((it + 1) * 32) * CC + koff[i]);
                vreg[i] = *(const f16x8*)(vp + (size_t)((it + 1) * 32) + voff[i]);
            }
        }

        // ---- QK^T: 16 rows x 32 m ----
        f32x4 s[2];
        s[0] = (f32x4){0.f, 0.f, 0.f, 0.f};
        s[1] = (f32x4){0.f, 0.f, 0.f, 0.f};
        __builtin_amdgcn_s_setprio(1);
#pragma unroll
        for (int kc = 0; kc < 8; ++kc) {
            f16x8 k0 = klds[kc * 64 + lane];
            f16x8 k1 = klds[(8 + kc) * 64 + lane];
            s[0] = __builtin_amdgcn_mfma_f32_16x16x32_f16(qf[kc], k0, s[0], 0, 0, 0);
            s[1] = __builtin_amdgcn_mfma_f32_16x16x32_f16(qf[kc], k1, s[1], 0, 0, 0);
        }
        __builtin_amdgcn_s_setprio(0);

        // ---- tail mask: columns beyond F_b get exactly zero weight ----
        if (((it + 1) << 5) > Fb) {
#pragma unroll
            for (int ms = 0; ms < 2; ++ms)
                if (it * 32 + ms * 16 + l16 >= Fb) {
#pragma unroll
                    for (int r = 0; r < 4; ++r) s[ms][r] = -3.0e38f;
                }
        }

        // ---- defer-max (T13): rescale only when tile max exceeds M+8 ----
        bool up = false;
#pragma unroll
        for (int ms = 0; ms < 2; ++ms)
#pragma unroll
            for (int r = 0; r < 4; ++r) up |= (s[ms][r] > M[r] + 8.0f);
        if (__any(up)) {
            float alpha[4];
#pragma unroll
            for (int r = 0; r < 4; ++r) {
                float tm = fmaxf(s[0][r], s[1][r]);
                tm = fmaxf(tm, __shfl_xor(tm, 1, 64));
                tm = fmaxf(tm, __shfl_xor(tm, 2, 64));
                tm = fmaxf(tm, __shfl_xor(tm, 4, 64));
                tm = fmaxf(tm, __shfl_xor(tm, 8, 64));
                float Mn = fmaxf(M[r], tm);
                alpha[r] = __expf(M[r] - Mn);
                M[r] = Mn;
            }
#pragma unroll
            for (int cs = 0; cs < 17; ++cs)
#pragma unroll
                for (int r = 0; r < 4; ++r) oacc[cs][r] *= alpha[r];
        }
        // P = exp(s - M)  (bounded by e^8), write per-wave P tile
#pragma unroll
        for (int ms = 0; ms < 2; ++ms)
#pragma unroll
            for (int r = 0; r < 4; ++r)
                pw[(quad * 4 + r) * 40 + ms * 16 + l16] = (f16)__expf(s[ms][r] - M[r]);
        asm volatile("s_waitcnt lgkmcnt(0)" ::: "memory");
        f16x8 pf = *(const f16x8*)(pw + l16 * 40 + quad * 8);

        // ---- PV: 16 rows x 256 c (+ L column) ----
        __builtin_amdgcn_s_setprio(1);
#pragma unroll
        for (int cs = 0; cs < 16; ++cs) {
            f16x8 vf = vlds[cs * 64 + lane];
            oacc[cs] = __builtin_amdgcn_mfma_f32_16x16x32_f16(pf, vf, oacc[cs], 0, 0, 0);
        }
        oacc[16] = __builtin_amdgcn_mfma_f32_16x16x32_f16(pf, ones, oacc[16], 0, 0, 0);
        __builtin_amdgcn_s_setprio(0);

        // all waves done reading klds/vlds before next iter's ds_write
        __syncthreads();
    }

    // ---- analytic fg column (z=0 only): score q.bk, weight F_f, value bv ----
    if (z == 0) {
        float cnn = 0.f;
#pragma unroll
        for (int kc = 0; kc < 8; ++kc) {
            const float* bkp = bk + kc * 32 + quad * 8;
#pragma unroll
            for (int j = 0; j < 8; ++j)
                cnn += (float)qf[kc][j] * bkp[j];
        }
        cnn += __shfl_xor(cnn, 16, 64);
        cnn += __shfl_xor(cnn, 32, 64);
        const float Ffw = (float)Ff;      // fg column multiplicity = F_f
        float aw[4], wv[4];
#pragma unroll
        for (int r = 0; r < 4; ++r) {
            float cr = __shfl(cnn, quad * 4 + r, 64);
            float Mn = fmaxf(M[r], cr);
            aw[r] = __expf(M[r] - Mn);
            wv[r] = Ffw * __expf(cr - Mn);
            M[r] = Mn;
        }
#pragma unroll
        for (int cs = 0; cs < 16; ++cs) {
            float bvc = bv[cs * 16 + l16];
#pragma unroll
            for (int r = 0; r < 4; ++r)
                oacc[cs][r] = oacc[cs][r] * aw[r] + wv[r] * bvc;
        }
#pragma unroll
        for (int r = 0; r < 4; ++r)
            oacc[16][r] = oacc[16][r] * aw[r] + wv[r];
    }

    // ---- partial epilogue: write O/L (f16), L, M for this half ----
    float inv[4];
#pragma unroll
    for (int r = 0; r < 4; ++r) {
        float Lr = oacc[16][r];
        inv[r] = (Lr > 0.f) ? 1.0f / Lr : 0.f;   // empty half -> store 0, w=0
    }
#pragma unroll
    for (int r = 0; r < 4; ++r) {
        int row = n0 + w * 16 + quad * 4 + r;
        f16* pp = (row < 2048)
                ? base + 3 * NM + (size_t)z * PMAIN + (size_t)row * 256
                : base + OFF_OVF + (size_t)z * 65536 + (size_t)(row - 2048) * 256;
#pragma unroll
        for (int cs = 0; cs < 16; ++cs)
            pp[cs * 16 + l16] = (f16)(oacc[cs][r] * inv[r]);
    }
    if (l16 == 0) {
        float* LMw = (float*)(base + OFF_LM);
#pragma unroll
        for (int r = 0; r < 4; ++r) {
            int row = n0 + w * 16 + quad * 4 + r;
            LMw[((size_t)z * QCAP + row) * 2 + 0] = oacc[16][r];
            LMw[((size_t)z * QCAP + row) * 2 + 1] = M[r];
        }
    }
}

// ---------------------------------------------------------------------------
// combine: grid (nb, 64) over ORIGINAL n-tiles (2 blocks/CU, coalesced out).
// Per row: crow = posf[n] (fg) or F_f (bg -> shared bq row). Gather both
// halves' partials, merge by softmax weights, stage into the verified
// fragment-major LDS layout, then the verbatim final MFMA phase.
// ---------------------------------------------------------------------------
__global__ __launch_bounds__(256, 2) void combine_kernel(
    const f16* __restrict__ wsh, const float* __restrict__ bo,
    const float* __restrict__ x, const float* __restrict__ gamma,
    float* __restrict__ outall, int b0)
{
    __shared__ f16x8 ot[2048];   // 32 KB merged-O tile, fragment-major

    const int t = threadIdx.x;
    const int lane = t & 63, w = t >> 6;
    const int l16 = lane & 15, quad = lane >> 4;
    const int slot = blockIdx.x;
    const int b = b0 + slot;
    const int n0 = blockIdx.y * 64;

    const f16* base = wsh + (size_t)slot * 4 * NM;
    const int* pof = (const int*)(base + OFF_POSF);
    const int* cn  = (const int*)(base + OFF_CNT);
    const int Ff = cn[1];
    const float* LMp = (const float*)(base + OFF_LM);
    const f16* wo16 = wsh + OFF_W16 + (size_t)3 * 65536;

#pragma unroll
    for (int i = 0; i < 8; ++i) {
        int u = i * 256 + t;
        int ul16 = u & 15, uq = (u >> 4) & 3, unc = (u >> 6) & 3, ukc = u >> 8;
        int orign = n0 + unc * 16 + ul16;
        int pfv = pof[orign];
        int crow = (pfv >= 0) ? pfv : Ff;
        int c0 = ukc * 32 + uq * 8;
        const f16* p0 = (crow < 2048)
                      ? base + 3 * NM + (size_t)crow * 256
                      : base + OFF_OVF + (size_t)(crow - 2048) * 256;
        const f16* p1 = (crow < 2048)
                      ? base + 3 * NM + PMAIN + (size_t)crow * 256
                      : base + OFF_OVF + 65536 + (size_t)(crow - 2048) * 256;
        f16x8 o0 = *(const f16x8*)(p0 + c0);
        f16x8 o1 = *(const f16x8*)(p1 + c0);
        float L0 = LMp[(size_t)crow * 2], M0 = LMp[(size_t)crow * 2 + 1];
        float L1 = LMp[((size_t)QCAP + crow) * 2], M1 = LMp[((size_t)QCAP + crow) * 2 + 1];
        float Mx = fmaxf(M0, M1);
        float w0 = L0 * __expf(M0 - Mx);
        float w1 = L1 * __expf(M1 - Mx);
        float inv = 1.0f / (w0 + w1);
        f16x8 om;
#pragma unroll
        for (int j = 0; j < 8; ++j)
            om[j] = (f16)((w0 * (float)o0[j] + w1 * (float)o1[j]) * inv);
        ot[u] = om;
    }
    __syncthreads();

    // final MFMA phase (verbatim from the verified final_kernel)
    const float* xp = x + (size_t)b * NM;
    float* outp = outall + (size_t)b * NM;
    float g = gamma[0];
#pragma unroll
    for (int pr = 0; pr < 2; ++pr) {
        int oc0 = w * 4 + pr * 2;
        f16x8 wf[2][8];
#pragma unroll
        for (int h = 0; h < 2; ++h) {
            const f16* wrow = wo16 + (size_t)((oc0 + h) * 16 + l16) * CC + quad * 8;
#pragma unroll
            for (int kc = 0; kc < 8; ++kc)
                wf[h][kc] = *(const f16x8*)(wrow + kc * 32);
        }
        f32x4 acc[2][4];
#pragma unroll
        for (int h = 0; h < 2; ++h)
#pragma unroll
            for (int nc = 0; nc < 4; ++nc) acc[h][nc] = (f32x4){0.f, 0.f, 0.f, 0.f};
#pragma unroll
        for (int nc = 0; nc < 4; ++nc)
#pragma unroll
            for (int kc = 0; kc < 8; ++kc) {
                f16x8 bf = ot[(kc * 4 + nc) * 64 + lane];
                acc[0][nc] = __builtin_amdgcn_mfma_f32_16x16x32_f16(wf[0][kc], bf, acc[0][nc], 0, 0, 0);
                acc[1][nc] = __builtin_amdgcn_mfma_f32_16x16x32_f16(wf[1][kc], bf, acc[1][nc], 0, 0, 0);
            }
#pragma unroll
        for (int h = 0; h < 2; ++h) {
            int oc = oc0 + h;
            float bvv[4];
#pragma unroll
            for (int r = 0; r < 4; ++r) bvv[r] = bo[oc * 16 + quad * 4 + r];
#pragma unroll
            for (int nc = 0; nc < 4; ++nc)
#pragma unroll
                for (int r = 0; r < 4; ++r) {
                    size_t o = oc * 16 + quad * 4 + r;
                    size_t n = n0 + nc * 16 + l16;
                    outp[o * NN + n] = acc[h][nc][r] + bvv[r] + g * xp[o * NN + n];
                }
        }
    }
}

// ---------------------------------------------------------------------------
__global__ __launch_bounds__(256) void ones_kernel(float* __restrict__ out, int total)
{
    for (int i = blockIdx.x * 256 + threadIdx.x; i < total; i += gridDim.x * 256)
        out[i] = 1.0f;
}

// ---------------------------------------------------------------------------
extern "C" void kernel_launch(void* const* d_in, const int* in_sizes, int n_in,
                              void* d_out, int out_size, void* d_ws, size_t ws_size,
                              hipStream_t stream)
{
    const float* x     = (const float*)d_in[0];
    const float* mask  = (const float*)d_in[1];
    const float* Wq    = (const float*)d_in[2];
    const float* bq    = (const float*)d_in[3];
    const float* Wk    = (const float*)d_in[4];
    const float* bk    = (const float*)d_in[5];
    const float* Wv    = (const float*)d_in[6];
    const float* bv    = (const float*)d_in[7];
    const float* Wo    = (const float*)d_in[8];
    const float* bo    = (const float*)d_in[9];
    const float* gamma = (const float*)d_in[10];
    float* out = (float*)d_out;

    const size_t slot_bytes = 4 * NM * sizeof(f16);   // 8 MiB
    f16* wsh = (f16*)d_ws;
    int nb = (int)(ws_size / slot_bytes);
    if (nb < 1) {
        ones_kernel<<<2048, 256, 0, stream>>>(out, out_size);
        return;
    }
    if (nb > NB) nb = NB;

    f16* w16 = wsh + OFF_W16;          // slot 0 plane-0 tail
    wprep_kernel<<<64, 256, 0, stream>>>(Wq, Wk, Wv, Wo, w16);

    for (int b0 = 0; b0 < NB; b0 += nb) {
        int nbc = NB - b0; if (nbc > nb) nbc = nb;
        mask_scan_kernel<<<nbc, 256, 0, stream>>>(mask, wsh, b0);
        dim3 gP(nbc, NN / 64);                 // slot-major: slot -> XCD
        dim3 gF(nbc, (QCAP / 64) * 2);         // 36 q-tiles x 2 m-halves = 576 blocks
        dim3 gC(nbc, NN / 64);
        proj_fused_kernel<<<gP, 512, 0, stream>>>(x, mask, w16, bq, bk, bv, wsh, b0);
        flash_kernel<<<gF, 256, 0, stream>>>(wsh, bk, bv, b0);
        combine_kernel<<<gC, 256, 0, stream>>>(wsh, bo, x, gamma, out, b0);
    }
}

// Round 17
// 273.144 us; speedup vs baseline: 1.0982x; 1.0206x over previous
//
#include <hip/hip_runtime.h>

#define CC 256
#define NN 4096
#define NB 8
#define NM ((size_t)CC * NN)   // 1M f16 elems per plane

// per-slot plane-0 tail layout (f16-unit offsets within the slot's plane 0).
#define OFF_OVF   589824   // partial rows 2048..2303:  + z*65536 + (row-2048)*256
#define OFF_LM    720896   // float[(z*2304 + row)*2] = {L, M}
#define OFF_POSM  739328   // int[4096] bg compact index or -1
#define OFF_POSF  747520   // int[4096] fg compact index or -1
#define OFF_CNT   755712   // int[2] = {F_b, F_f}
#define OFF_W16   755776   // slot 0 only: f16[4*65536] = Wq,Wk,Wv,Wo
#define PMAIN     524288   // plane 3: + z*PMAIN + row*256, rows 0..2047
#define QCAP      2304     // max compacted q rows (F_f+1; 8 sigma bound)

typedef _Float16 f16;
typedef f16 f16x4 __attribute__((ext_vector_type(4)));
typedef f16 f16x8 __attribute__((ext_vector_type(8)));
typedef float f32x4 __attribute__((ext_vector_type(4)));
typedef unsigned int u32;

// ---------------------------------------------------------------------------
// prep: fused wprep + mask_scan (saves one launch + serialization gap).
// blocks [0,64): f32->f16 convert of Wq/Wk/Wv/Wo into slot-0 plane-0 tail.
// blocks [64, 64+nbc): per-slot mask compactions posm/posf/cnts.
// ---------------------------------------------------------------------------
__global__ __launch_bounds__(256) void prep_kernel(
    const float* __restrict__ Wq, const float* __restrict__ Wk,
    const float* __restrict__ Wv, const float* __restrict__ Wo,
    const float* __restrict__ mask, f16* __restrict__ wsh, int b0)
{
    const int blk = blockIdx.x;
    const int t = threadIdx.x;
    if (blk < 64) {
        f16* w16 = wsh + OFF_W16;
        int i = (blk * 256 + t) * 4;
        float4 a = *(const float4*)(Wq + i);
        float4 b = *(const float4*)(Wk + i);
        float4 c = *(const float4*)(Wv + i);
        float4 d = *(const float4*)(Wo + i);
        f16x4 ha, hb, hc, hd;
        ha[0]=(f16)a.x; ha[1]=(f16)a.y; ha[2]=(f16)a.z; ha[3]=(f16)a.w;
        hb[0]=(f16)b.x; hb[1]=(f16)b.y; hb[2]=(f16)b.z; hb[3]=(f16)b.w;
        hc[0]=(f16)c.x; hc[1]=(f16)c.y; hc[2]=(f16)c.z; hc[3]=(f16)c.w;
        hd[0]=(f16)d.x; hd[1]=(f16)d.y; hd[2]=(f16)d.z; hd[3]=(f16)d.w;
        *(f16x4*)(w16 + i)            = ha;
        *(f16x4*)(w16 + 65536 + i)    = hb;
        *(f16x4*)(w16 + 131072 + i)   = hc;
        *(f16x4*)(w16 + 196608 + i)   = hd;
        return;
    }
    const int slot = blk - 64;
    const int b = b0 + slot;
    const int lane = t & 63, w = t >> 6;
    __shared__ int wsum0[4], wsum1[4];
    const float* mp = mask + (size_t)b * NN;
    f16* base = wsh + (size_t)slot * 4 * NM;
    int* pm = (int*)(base + OFF_POSM);
    int* pf = (int*)(base + OFF_POSF);
    int* cn = (int*)(base + OFF_CNT);

    int loc0[16], loc1[16], c0 = 0, c1 = 0;
    float mv[16];
#pragma unroll
    for (int i = 0; i < 16; ++i) {
        mv[i] = mp[t * 16 + i];
        loc0[i] = c0; loc1[i] = c1;
        if (mv[i] == 0.0f) ++c0; else ++c1;
    }
    int i0 = c0, i1 = c1;
#pragma unroll
    for (int d = 1; d < 64; d <<= 1) {
        int v0 = __shfl_up(i0, d, 64);
        int v1 = __shfl_up(i1, d, 64);
        if (lane >= d) { i0 += v0; i1 += v1; }
    }
    if (lane == 63) { wsum0[w] = i0; wsum1[w] = i1; }
    int e0 = i0 - c0, e1 = i1 - c1;
    __syncthreads();
    int s0 = e0, s1 = e1;
    for (int i = 0; i < w; ++i) { s0 += wsum0[i]; s1 += wsum1[i]; }
#pragma unroll
    for (int i = 0; i < 16; ++i) {
        pm[t * 16 + i] = (mv[i] == 0.0f) ? (s0 + loc0[i]) : -1;
        pf[t * 16 + i] = (mv[i] != 0.0f) ? (s1 + loc1[i]) : -1;
    }
    if (t == 0) {
        cn[0] = wsum0[0] + wsum0[1] + wsum0[2] + wsum0[3];
        cn[1] = wsum1[0] + wsum1[1] + wsum1[2] + wsum1[3];
    }
}

// ---------------------------------------------------------------------------
// proj_fused v3: q compacted to fg rows (posf scatter) + bq row at q[F_f] +
// q tail zeroed. k/v compacted (posm). (unchanged from R13..R16)
// ---------------------------------------------------------------------------
__global__ __launch_bounds__(512, 4) void proj_fused_kernel(
    const float* __restrict__ x, const float* __restrict__ mask,
    const f16* __restrict__ w16, const float* __restrict__ bq,
    const float* __restrict__ bk, const float* __restrict__ bv,
    f16* __restrict__ wsh, int b0)
{
    __shared__ f16x8 xf[2048];   // 32 KB, (x*m) fragment-major
    __shared__ f16x8 xb[2048];   // 32 KB, (x*(1-m))

    const int t = threadIdx.x;
    const int lane = t & 63, w = t >> 6;          // w in [0,8)
    const int l16 = lane & 15, quad = lane >> 4;
    const int slot = blockIdx.x;
    const int b = b0 + slot;
    const int n0 = blockIdx.y * 64;
    const float* xp = x + (size_t)b * NM;
    f16* base = wsh + (size_t)slot * 4 * NM;
    const int* pom = (const int*)(base + OFF_POSM);
    const int* pof = (const int*)(base + OFF_POSF);
    const int* cn  = (const int*)(base + OFF_CNT);

    float mf  = mask[(size_t)b * NN + n0 + lane];
    float mbk = 1.0f - mf;
#pragma unroll
    for (int i = 0; i < 4; ++i) {                 // 8 waves x 4 groups = 256 c
        int cb = w * 4 + i;
        const float* col = xp + (size_t)cb * 8 * NN + n0 + lane;
        f16x8 vf, vb;
#pragma unroll
        for (int u = 0; u < 8; ++u) {
            float xv = col[(size_t)u * NN];
            vf[u] = (f16)(xv * mf);
            vb[u] = (f16)(xv * mbk);
        }
        int unit = ((cb >> 2) * 4 + (lane >> 4)) * 64 + (cb & 3) * 16 + (lane & 15);
        xf[unit] = vf;
        xb[unit] = vb;
    }
    __syncthreads();

#pragma unroll
    for (int pr = 0; pr < 3; ++pr) {              // 8 waves x 3 pairs = 48 jobs
        int j0  = w * 6 + pr * 2;
        int p   = j0 >> 4;
        int oc0 = j0 & 15;
        const f16* Wp     = w16 + (size_t)p * 65536;
        const float* bias = (p == 0) ? bq : (p == 1) ? bk : bv;
        const f16x8* bt   = (p == 0) ? xf : xb;

        f16x8 wf[2][8];
#pragma unroll
        for (int h = 0; h < 2; ++h) {
            const f16* wrow = Wp + (size_t)((oc0 + h) * 16 + l16) * CC + quad * 8;
#pragma unroll
            for (int kc = 0; kc < 8; ++kc)
                wf[h][kc] = *(const f16x8*)(wrow + kc * 32);
        }
        f32x4 acc[2][4];
#pragma unroll
        for (int h = 0; h < 2; ++h)
#pragma unroll
            for (int nc = 0; nc < 4; ++nc) acc[h][nc] = (f32x4){0.f, 0.f, 0.f, 0.f};
#pragma unroll
        for (int nc = 0; nc < 4; ++nc)
#pragma unroll
            for (int kc = 0; kc < 8; ++kc) {
                f16x8 bf = bt[(kc * 4 + nc) * 64 + lane];
                acc[0][nc] = __builtin_amdgcn_mfma_f32_16x16x32_f16(wf[0][kc], bf, acc[0][nc], 0, 0, 0);
                acc[1][nc] = __builtin_amdgcn_mfma_f32_16x16x32_f16(wf[1][kc], bf, acc[1][nc], 0, 0, 0);
            }
#pragma unroll
        for (int h = 0; h < 2; ++h) {
            int oc = oc0 + h;
            float bvv[4];
#pragma unroll
            for (int r = 0; r < 4; ++r) bvv[r] = bias[oc * 16 + quad * 4 + r];
            if (p == 2) {                        // v [C][M] column-scatter (bg)
                f16* vpl = base + 2 * NM;
#pragma unroll
                for (int nc = 0; nc < 4; ++nc) {
                    int cp = pom[n0 + nc * 16 + l16];
                    if (cp >= 0) {
#pragma unroll
                        for (int r = 0; r < 4; ++r)
                            vpl[(size_t)(oc * 16 + quad * 4 + r) * NN + cp] =
                                (f16)(acc[h][nc][r] + bvv[r]);
                    }
                }
            } else if (p == 1) {                 // k [M][C] row-scatter (bg)
                f16* kpl = base + NM;
#pragma unroll
                for (int nc = 0; nc < 4; ++nc) {
                    int cp = pom[n0 + nc * 16 + l16];
                    if (cp >= 0) {
                        f16x4 pk;
#pragma unroll
                        for (int r = 0; r < 4; ++r) pk[r] = (f16)(acc[h][nc][r] + bvv[r]);
                        *(f16x4*)(kpl + (size_t)cp * CC + oc * 16 + quad * 4) = pk;
                    }
                }
            } else {                             // q [Qc][C] row-scatter (fg)
#pragma unroll
                for (int nc = 0; nc < 4; ++nc) {
                    int cp = pof[n0 + nc * 16 + l16];
                    if (cp >= 0) {
                        f16x4 pk;
#pragma unroll
                        for (int r = 0; r < 4; ++r) pk[r] = (f16)(acc[h][nc][r] + bvv[r]);
                        *(f16x4*)(base + (size_t)cp * CC + oc * 16 + quad * 4) = pk;
                    }
                }
            }
        }
    }

    // pad/aux section, once per slot
    if (blockIdx.y == 0) {
        int Fb = cn[0], Ff = cn[1];
        f16x8 z8;
#pragma unroll
        for (int i = 0; i < 8; ++i) z8[i] = (f16)0.0f;
        {
            int Mp = (Fb + 31) & ~31;
            int pad = Mp - Fb;
            if (pad > 0) {
                f16* kpl = base + NM;
                f16* vpl = base + 2 * NM;
                for (int idx = t; idx < pad * 32; idx += 512)
                    *(f16x8*)(kpl + (size_t)(Fb + idx / 32) * CC + (idx & 31) * 8) = z8;
                for (int idx = t; idx < pad * CC; idx += 512)
                    vpl[(size_t)(idx / pad) * NN + Fb + (idx % pad)] = (f16)0.0f;
            }
        }
        // bq row at q[Ff] (the shared bg query), f16
        for (int c = t; c < CC; c += 512)
            base[(size_t)Ff * CC + c] = (f16)bq[c];
        // zero q tail rows Ff+1 .. ceil64(Ff+1)-1
        {
            int qe = (Ff + 64) & ~63;
            int nz = qe - (Ff + 1);
            for (int idx = t; idx < nz * 32; idx += 512)
                *(f16x8*)(base + (size_t)(Ff + 1 + idx / 32) * CC + (idx & 31) * 8) = z8;
        }
    }
}

// ---------------------------------------------------------------------------
// flash v13 (FROZEN from R16, session-best 127 us): q+m compacted, defer-max,
// ones-column L, analytic fg column, partial O/L/M output; register-staged
// prefetch into a single 38 KB LDS buffer (R0 skeleton, no vmcnt asm).
// ---------------------------------------------------------------------------
__global__ __launch_bounds__(256, 2) void flash_kernel(
    f16* __restrict__ wsh, const float* __restrict__ bk,
    const float* __restrict__ bv, int b0)
{
    __shared__ f16x8 klds[1024];       // 16 KB : 32m x 256c fragment-major
    __shared__ f16x8 vlds[1024];       // 16 KB : [c][m] fragment-major
    __shared__ f16 pbuf[4][16 * 40];   // 5 KB, per-wave P tile, stride 40

    const int t    = threadIdx.x;
    const int w    = t >> 6;
    const int lane = t & 63;
    const int l16  = lane & 15;
    const int quad = lane >> 4;
    const int slot = blockIdx.x;
    const int n0   = (blockIdx.y >> 1) * 64;  // compacted q-row tile base
    const int z    = blockIdx.y & 1;          // m-half

    f16* base = wsh + (size_t)slot * 4 * NM;
    const int* cn = (const int*)(base + OFF_CNT);
    const int Fb = cn[0], Ff = cn[1];
    if (n0 > Ff) return;               // tile entirely beyond the bq row

    const f16* qt = base;              // [Qc][C] compacted (+bq row Ff)
    const f16* kt = base + NM;         // [M][C] compacted bg
    const f16* vp = base + 2 * NM;     // [C][M] compacted bg

    const int nt  = (Fb + 31) >> 5;
    const int h   = (nt + 1) >> 1;
    const int mt0 = z ? h : 0;
    const int mt1 = z ? nt : h;

    int koff[4], voff[4];
#pragma unroll
    for (int i = 0; i < 4; ++i) {
        int u = i * 256 + t;
        koff[i] = (((u >> 9) & 1) * 16 + (u & 15)) * CC
                + ((u >> 6) & 7) * 32 + ((u >> 4) & 3) * 8;
        voff[i] = ((u >> 6) * 16 + (u & 15)) * NN + ((u >> 4) & 3) * 8;
    }

    // Q fragments for this wave's 16 compacted rows
    const int nrow = n0 + w * 16 + l16;
    f16x8 qf[8];
#pragma unroll
    for (int kc = 0; kc < 8; ++kc)
        qf[kc] = *(const f16x8*)(qt + (size_t)nrow * CC + kc * 32 + quad * 8);

    f32x4 oacc[17];                    // [0..15]: O cols; [16]: row-sum L
#pragma unroll
    for (int i = 0; i < 17; ++i) oacc[i] = (f32x4){0.f, 0.f, 0.f, 0.f};
    float M[4] = {-3.0e38f, -3.0e38f, -3.0e38f, -3.0e38f};

    f16* pw = &pbuf[w][0];
    f16x8 ones;
#pragma unroll
    for (int i = 0; i < 8; ++i) ones[i] = (f16)1.0f;

    // prologue: stage first tile into registers
    f16x8 kreg[4], vreg[4];
    if (mt1 > mt0) {
#pragma unroll
        for (int i = 0; i < 4; ++i) {
            kreg[i] = *(const f16x8*)(kt + (size_t)(mt0 * 32) * CC + koff[i]);
            vreg[i] = *(const f16x8*)(vp + (size_t)(mt0 * 32) + voff[i]);
        }
    }

    for (int it = mt0; it < mt1; ++it) {
        // write staged regs to LDS (compiler waits the loads here)
#pragma unroll
        for (int i = 0; i < 4; ++i) {
            klds[i * 256 + t] = kreg[i];
            vlds[i * 256 + t] = vreg[i];
        }
        __syncthreads();
        // prefetch next tile into regs; latency hides under compute below
        if (it + 1 < mt1) {
#pragma unroll
            for (int i = 0; i < 4; ++i) {
                kreg[i] = *(const f16x8*)(kt + (size_t)((it + 1) * 32) * CC + koff[i]);
                vreg[i] = *(const f16x8*)(vp + (size_t)((it + 1) * 32) + voff[i]);
            }
        }

        // ---- QK^T: 16 rows x 32 m ----
        f32x4 s[2];
        s[0] = (f32x4){0.f, 0.f, 0.f, 0.f};
        s[1] = (f32x4){0.f, 0.f, 0.f, 0.f};
        __builtin_amdgcn_s_setprio(1);
#pragma unroll
        for (int kc = 0; kc < 8; ++kc) {
            f16x8 k0 = klds[kc * 64 + lane];
            f16x8 k1 = klds[(8 + kc) * 64 + lane];
            s[0] = __builtin_amdgcn_mfma_f32_16x16x32_f16(qf[kc], k0, s[0], 0, 0, 0);
            s[1] = __builtin_amdgcn_mfma_f32_16x16x32_f16(qf[kc], k1, s[1], 0, 0, 0);
        }
        __builtin_amdgcn_s_setprio(0);

        // ---- tail mask: columns beyond F_b get exactly zero weight ----
        if (((it + 1) << 5) > Fb) {
#pragma unroll
            for (int ms = 0; ms < 2; ++ms)
                if (it * 32 + ms * 16 + l16 >= Fb) {
#pragma unroll
                    for (int r = 0; r < 4; ++r) s[ms][r] = -3.0e38f;
                }
        }

        // ---- defer-max (T13): rescale only when tile max exceeds M+8 ----
        bool up = false;
#pragma unroll
        for (int ms = 0; ms < 2; ++ms)
#pragma unroll
            for (int r = 0; r < 4; ++r) up |= (s[ms][r] > M[r] + 8.0f);
        if (__any(up)) {
            float alpha[4];
#pragma unroll
            for (int r = 0; r < 4; ++r) {
                float tm = fmaxf(s[0][r], s[1][r]);
                tm = fmaxf(tm, __shfl_xor(tm, 1, 64));
                tm = fmaxf(tm, __shfl_xor(tm, 2, 64));
                tm = fmaxf(tm, __shfl_xor(tm, 4, 64));
                tm = fmaxf(tm, __shfl_xor(tm, 8, 64));
                float Mn = fmaxf(M[r], tm);
                alpha[r] = __expf(M[r] - Mn);
                M[r] = Mn;
            }
#pragma unroll
            for (int cs = 0; cs < 17; ++cs)
#pragma unroll
                for (int r = 0; r < 4; ++r) oacc[cs][r] *= alpha[r];
        }
        // P = exp(s - M)  (bounded by e^8), write per-wave P tile
#pragma unroll
        for (int ms = 0; ms < 2; ++ms)
#pragma unroll
            for (int r = 0; r < 4; ++r)
                pw[(quad * 4 + r) * 40 + ms * 16 + l16] = (f16)__expf(s[ms][r] - M[r]);
        asm volatile("s_waitcnt lgkmcnt(0)" ::: "memory");
        f16x8 pf = *(const f16x8*)(pw + l16 * 40 + quad * 8);

        // ---- PV: 16 rows x 256 c (+ L column) ----
        __builtin_amdgcn_s_setprio(1);
#pragma unroll
        for (int cs = 0; cs < 16; ++cs) {
            f16x8 vf = vlds[cs * 64 + lane];
            oacc[cs] = __builtin_amdgcn_mfma_f32_16x16x32_f16(pf, vf, oacc[cs], 0, 0, 0);
        }
        oacc[16] = __builtin_amdgcn_mfma_f32_16x16x32_f16(pf, ones, oacc[16], 0, 0, 0);
        __builtin_amdgcn_s_setprio(0);

        // all waves done reading klds/vlds before next iter's ds_write
        __syncthreads();
    }

    // ---- analytic fg column (z=0 only): score q.bk, weight F_f, value bv ----
    if (z == 0) {
        float cnn = 0.f;
#pragma unroll
        for (int kc = 0; kc < 8; ++kc) {
            const float* bkp = bk + kc * 32 + quad * 8;
#pragma unroll
            for (int j = 0; j < 8; ++j)
                cnn += (float)qf[kc][j] * bkp[j];
        }
        cnn += __shfl_xor(cnn, 16, 64);
        cnn += __shfl_xor(cnn, 32, 64);
        const float Ffw = (float)Ff;      // fg column multiplicity = F_f
        float aw[4], wv[4];
#pragma unroll
        for (int r = 0; r < 4; ++r) {
            float cr = __shfl(cnn, quad * 4 + r, 64);
            float Mn = fmaxf(M[r], cr);
            aw[r] = __expf(M[r] - Mn);
            wv[r] = Ffw * __expf(cr - Mn);
            M[r] = Mn;
        }
#pragma unroll
        for (int cs = 0; cs < 16; ++cs) {
            float bvc = bv[cs * 16 + l16];
#pragma unroll
            for (int r = 0; r < 4; ++r)
                oacc[cs][r] = oacc[cs][r] * aw[r] + wv[r] * bvc;
        }
#pragma unroll
        for (int r = 0; r < 4; ++r)
            oacc[16][r] = oacc[16][r] * aw[r] + wv[r];
    }

    // ---- partial epilogue: write O/L (f16), L, M for this half ----
    float inv[4];
#pragma unroll
    for (int r = 0; r < 4; ++r) {
        float Lr = oacc[16][r];
        inv[r] = (Lr > 0.f) ? 1.0f / Lr : 0.f;   // empty half -> store 0, w=0
    }
#pragma unroll
    for (int r = 0; r < 4; ++r) {
        int row = n0 + w * 16 + quad * 4 + r;
        f16* pp = (row < 2048)
                ? base + 3 * NM + (size_t)z * PMAIN + (size_t)row * 256
                : base + OFF_OVF + (size_t)z * 65536 + (size_t)(row - 2048) * 256;
#pragma unroll
        for (int cs = 0; cs < 16; ++cs)
            pp[cs * 16 + l16] = (f16)(oacc[cs][r] * inv[r]);
    }
    if (l16 == 0) {
        float* LMw = (float*)(base + OFF_LM);
#pragma unroll
        for (int r = 0; r < 4; ++r) {
            int row = n0 + w * 16 + quad * 4 + r;
            LMw[((size_t)z * QCAP + row) * 2 + 0] = oacc[16][r];
            LMw[((size_t)z * QCAP + row) * 2 + 1] = M[r];
        }
    }
}

// ---------------------------------------------------------------------------
// combine v2: 512 threads / 8 waves (R17). Same math as R16's combine; the
// gather/merge stage is re-indexed for 512 threads (u = i*512+t, i<4) and the
// MFMA phase gives each of the 8 waves ONE oc0 pair (oc0 = w*2). combine is
// latency-bound (80 MB traffic = ~13 us floor vs ~35-40 us measured);
// doubling resident waves/SIMD (2 -> 4) overlaps the partial-gather and
// W-load chains.
// ---------------------------------------------------------------------------
__global__ __launch_bounds__(512, 4) void combine_kernel(
    const f16* __restrict__ wsh, const float* __restrict__ bo,
    const float* __restrict__ x, const float* __restrict__ gamma,
    float* __restrict__ outall, int b0)
{
    __shared__ f16x8 ot[2048];   // 32 KB merged-O tile, fragment-major

    const int t = threadIdx.x;
    const int lane = t & 63, w = t >> 6;      // w in [0,8)
    const int l16 = lane & 15, quad = lane >> 4;
    const int slot = blockIdx.x;
    const int b = b0 + slot;
    const int n0 = blockIdx.y * 64;

    const f16* base = wsh + (size_t)slot * 4 * NM;
    const int* pof = (const int*)(base + OFF_POSF);
    const int* cn  = (const int*)(base + OFF_CNT);
    const int Ff = cn[1];
    const float* LMp = (const float*)(base + OFF_LM);
    const f16* wo16 = wsh + OFF_W16 + (size_t)3 * 65536;

#pragma unroll
    for (int i = 0; i < 4; ++i) {
        int u = i * 512 + t;
        int ul16 = u & 15, uq = (u >> 4) & 3, unc = (u >> 6) & 3, ukc = u >> 8;
        int orign = n0 + unc * 16 + ul16;
        int pfv = pof[orign];
        int crow = (pfv >= 0) ? pfv : Ff;
        int c0 = ukc * 32 + uq * 8;
        const f16* p0 = (crow < 2048)
                      ? base + 3 * NM + (size_t)crow * 256
                      : base + OFF_OVF + (size_t)(crow - 2048) * 256;
        const f16* p1 = (crow < 2048)
                      ? base + 3 * NM + PMAIN + (size_t)crow * 256
                      : base + OFF_OVF + 65536 + (size_t)(crow - 2048) * 256;
        f16x8 o0 = *(const f16x8*)(p0 + c0);
        f16x8 o1 = *(const f16x8*)(p1 + c0);
        float L0 = LMp[(size_t)crow * 2], M0 = LMp[(size_t)crow * 2 + 1];
        float L1 = LMp[((size_t)QCAP + crow) * 2], M1 = LMp[((size_t)QCAP + crow) * 2 + 1];
        float Mx = fmaxf(M0, M1);
        float w0 = L0 * __expf(M0 - Mx);
        float w1 = L1 * __expf(M1 - Mx);
        float inv = 1.0f / (w0 + w1);
        f16x8 om;
#pragma unroll
        for (int j = 0; j < 8; ++j)
            om[j] = (f16)((w0 * (float)o0[j] + w1 * (float)o1[j]) * inv);
        ot[u] = om;
    }
    __syncthreads();

    // final MFMA phase: 8 waves, one oc0 pair each (covers oc 0..15)
    const float* xp = x + (size_t)b * NM;
    float* outp = outall + (size_t)b * NM;
    float g = gamma[0];
    {
        int oc0 = w * 2;
        f16x8 wf[2][8];
#pragma unroll
        for (int h = 0; h < 2; ++h) {
            const f16* wrow = wo16 + (size_t)((oc0 + h) * 16 + l16) * CC + quad * 8;
#pragma unroll
            for (int kc = 0; kc < 8; ++kc)
                wf[h][kc] = *(const f16x8*)(wrow + kc * 32);
        }
        f32x4 acc[2][4];
#pragma unroll
        for (int h = 0; h < 2; ++h)
#pragma unroll
            for (int nc = 0; nc < 4; ++nc) acc[h][nc] = (f32x4){0.f, 0.f, 0.f, 0.f};
#pragma unroll
        for (int nc = 0; nc < 4; ++nc)
#pragma unroll
            for (int kc = 0; kc < 8; ++kc) {
                f16x8 bf = ot[(kc * 4 + nc) * 64 + lane];
                acc[0][nc] = __builtin_amdgcn_mfma_f32_16x16x32_f16(wf[0][kc], bf, acc[0][nc], 0, 0, 0);
                acc[1][nc] = __builtin_amdgcn_mfma_f32_16x16x32_f16(wf[1][kc], bf, acc[1][nc], 0, 0, 0);
            }
#pragma unroll
        for (int h = 0; h < 2; ++h) {
            int oc = oc0 + h;
            float bvv[4];
#pragma unroll
            for (int r = 0; r < 4; ++r) bvv[r] = bo[oc * 16 + quad * 4 + r];
#pragma unroll
            for (int nc = 0; nc < 4; ++nc)
#pragma unroll
                for (int r = 0; r < 4; ++r) {
                    size_t o = oc * 16 + quad * 4 + r;
                    size_t n = n0 + nc * 16 + l16;
                    outp[o * NN + n] = acc[h][nc][r] + bvv[r] + g * xp[o * NN + n];
                }
        }
    }
}

// ---------------------------------------------------------------------------
__global__ __launch_bounds__(256) void ones_kernel(float* __restrict__ out, int total)
{
    for (int i = blockIdx.x * 256 + threadIdx.x; i < total; i += gridDim.x * 256)
        out[i] = 1.0f;
}

// ---------------------------------------------------------------------------
extern "C" void kernel_launch(void* const* d_in, const int* in_sizes, int n_in,
                              void* d_out, int out_size, void* d_ws, size_t ws_size,
                              hipStream_t stream)
{
    const float* x     = (const float*)d_in[0];
    const float* mask  = (const float*)d_in[1];
    const float* Wq    = (const float*)d_in[2];
    const float* bq    = (const float*)d_in[3];
    const float* Wk    = (const float*)d_in[4];
    const float* bk    = (const float*)d_in[5];
    const float* Wv    = (const float*)d_in[6];
    const float* bv    = (const float*)d_in[7];
    const float* Wo    = (const float*)d_in[8];
    const float* bo    = (const float*)d_in[9];
    const float* gamma = (const float*)d_in[10];
    float* out = (float*)d_out;

    const size_t slot_bytes = 4 * NM * sizeof(f16);   // 8 MiB
    f16* wsh = (f16*)d_ws;
    int nb = (int)(ws_size / slot_bytes);
    if (nb < 1) {
        ones_kernel<<<2048, 256, 0, stream>>>(out, out_size);
        return;
    }
    if (nb > NB) nb = NB;

    f16* w16 = wsh + OFF_W16;          // slot 0 plane-0 tail

    for (int b0 = 0; b0 < NB; b0 += nb) {
        int nbc = NB - b0; if (nbc > nb) nbc = nb;
        prep_kernel<<<64 + nbc, 256, 0, stream>>>(Wq, Wk, Wv, Wo, mask, wsh, b0);
        dim3 gP(nbc, NN / 64);                 // slot-major: slot -> XCD
        dim3 gF(nbc, (QCAP / 64) * 2);         // 36 q-tiles x 2 m-halves = 576 blocks
        dim3 gC(nbc, NN / 64);
        proj_fused_kernel<<<gP, 512, 0, stream>>>(x, mask, w16, bq, bk, bv, wsh, b0);
        flash_kernel<<<gF, 256, 0, stream>>>(wsh, bk, bv, b0);
        combine_kernel<<<gC, 512, 0, stream>>>(wsh, bo, x, gamma, out, b0);
    }
}